// Round 1
// baseline (182.245 us; speedup 1.0000x reference)
//
#include <hip/hip_runtime.h>

// ---------------------------------------------------------------------------
// SpatialWiseSelfAttention on MI355X (gfx950), bf16 MFMA pipeline.
//   x[16,512,32,32] -> xf[8192,1024]
//   Q/K/V = xf @ W*.T + b*      (NT GEMM, bf16 inputs, fp32 accum)
//   per (b,h): S = Q K^T / 8 ; P = softmax(S) ; O = P V
//   out = O @ Wo.T + bo  (fp32 out)
// ---------------------------------------------------------------------------

typedef unsigned short u16;
typedef __attribute__((ext_vector_type(8))) short short8;   // 8 bf16 = 4 VGPR
typedef __attribute__((ext_vector_type(4))) float f32x4;
typedef __attribute__((ext_vector_type(4))) unsigned short u16x4;

__device__ __forceinline__ u16 f2bf(float x) {            // RNE f32->bf16
  unsigned u = __float_as_uint(x);
  u += 0x7FFFu + ((u >> 16) & 1u);
  return (u16)(u >> 16);
}

__device__ __forceinline__ void async16(const void* g, void* l) {
  // 16B global->LDS direct; LDS dest = wave-uniform base + lane*16.
  __builtin_amdgcn_global_load_lds(
      (__attribute__((address_space(1))) unsigned int*)(g),
      (__attribute__((address_space(3))) unsigned int*)(l), 16, 0, 0);
}

// ---------------------------------------------------------------------------
// fp32 -> bf16 conversion, 4 elems/thread
// ---------------------------------------------------------------------------
__global__ __launch_bounds__(256) void cvt_bf16(const float* __restrict__ s,
                                                u16* __restrict__ d, int n4) {
  int i = blockIdx.x * 256 + threadIdx.x;
  if (i >= n4) return;
  f32x4 v = ((const f32x4*)s)[i];
  u16x4 o;
#pragma unroll
  for (int j = 0; j < 4; ++j) o[j] = f2bf(v[j]);
  ((u16x4*)d)[i] = o;
}

// ---------------------------------------------------------------------------
// m97-structure NT GEMM core: C[128x128] tile, BK=32, 256 thr / 4 waves (2x2),
// each wave 64x64 = 4x4 frags of 16x16x32 bf16 MFMA. K = 1024 fixed.
// A[M][1024] bf16 row-major, W[N][1024] bf16 row-major (B^T input).
// ---------------------------------------------------------------------------
__device__ __forceinline__ void gemm_tile(const u16* __restrict__ A,
                                          const u16* __restrict__ W,
                                          u16* lA, u16* lB,
                                          int m0, int n0, f32x4 acc[4][4]) {
  const int t = threadIdx.x;
  const int wave = t >> 6, lane = t & 63, lr = lane & 15, lg = lane >> 4;
  const int wr = wave >> 1, wc = wave & 1;
  const u16* ga = A + (m0 + (t >> 2)) * 1024 + (t & 3) * 8;
  const u16* gb = W + (n0 + (t >> 2)) * 1024 + (t & 3) * 8;
  u16* la0 = lA + wave * 512;            // elem offsets: thread t -> t*8
  u16* la1 = lA + 2048 + wave * 512;
  u16* lb0 = lB + wave * 512;
  u16* lb1 = lB + 2048 + wave * 512;
  const u16* pa = lA + (wr * 64 + lr) * 32 + lg * 8;  // A-frag: row=lr(+16*rb), k=lg*8..
  const u16* pb = lB + (wc * 64 + lr) * 32 + lg * 8;

  for (int k0 = 0; k0 < 1024; k0 += 32) {
    __syncthreads();                     // prior iter's LDS reads done
    async16(ga + k0, la0);               // A rows 0..63 of tile
    async16(ga + 65536 + k0, la1);       // A rows 64..127 (64*1024 elems)
    async16(gb + k0, lb0);
    async16(gb + 65536 + k0, lb1);
    __syncthreads();                     // drains vmcnt before reads
    short8 av[4], bv[4];
#pragma unroll
    for (int i = 0; i < 4; ++i) av[i] = *(const short8*)(pa + i * 512);
#pragma unroll
    for (int i = 0; i < 4; ++i) bv[i] = *(const short8*)(pb + i * 512);
#pragma unroll
    for (int i = 0; i < 4; ++i)
#pragma unroll
      for (int j = 0; j < 4; ++j)
        acc[i][j] = __builtin_amdgcn_mfma_f32_16x16x32_bf16(av[i], bv[j],
                                                            acc[i][j], 0, 0, 0);
  }
}

// QKV fused: grid (8, 64, 3); z selects {Q,K,V}. Q,K out layout [b,h,c,d];
// V out layout [b,h,d,c] (transposed so attention PV reads contiguous k).
__global__ __launch_bounds__(256) void gemm_qkv(
    const u16* __restrict__ xb, const u16* __restrict__ wq,
    const u16* __restrict__ wk, const u16* __restrict__ wv,
    const float* __restrict__ bq, const float* __restrict__ bk,
    const float* __restrict__ bv, u16* __restrict__ qo, u16* __restrict__ ko,
    u16* __restrict__ vo) {
  __shared__ u16 lA[4096], lB[4096];
  const int z = blockIdx.z;
  const u16* W = (z == 0) ? wq : (z == 1) ? wk : wv;
  const float* bias = (z == 0) ? bq : (z == 1) ? bk : bv;
  u16* outp = (z == 0) ? qo : (z == 1) ? ko : vo;
  const int m0 = blockIdx.y * 128, n0 = blockIdx.x * 128;
  f32x4 acc[4][4];
#pragma unroll
  for (int i = 0; i < 4; ++i)
#pragma unroll
    for (int j = 0; j < 4; ++j) acc[i][j] = (f32x4){0.f, 0.f, 0.f, 0.f};
  gemm_tile(xb, W, lA, lB, m0, n0, acc);

  const int t = threadIdx.x;
  const int wave = t >> 6, lane = t & 63, lr = lane & 15, lg = lane >> 4;
  const int wr = wave >> 1, wc = wave & 1;
  float bb[4];
#pragma unroll
  for (int cb = 0; cb < 4; ++cb) bb[cb] = bias[n0 + wc * 64 + cb * 16 + lr];
#pragma unroll
  for (int rb = 0; rb < 4; ++rb)
#pragma unroll
    for (int cb = 0; cb < 4; ++cb)
#pragma unroll
      for (int r = 0; r < 4; ++r) {
        int m = m0 + wr * 64 + rb * 16 + lg * 4 + r;  // D: row=(lane>>4)*4+reg
        int n = n0 + wc * 64 + cb * 16 + lr;          //    col=lane&15
        float val = acc[rb][cb][r] + bb[cb];
        int b_ = m >> 9, c = m & 511, h = n >> 6, dd = n & 63;
        int idx = (z == 2) ? ((((b_ << 4) + h) << 15) + (dd << 9) + c)
                           : ((((b_ << 4) + h) << 15) + (c << 6) + dd);
        outp[idx] = f2bf(val);
      }
}

// Output projection: fp32 out + bias, linear [8192][1024].
__global__ __launch_bounds__(256) void gemm_oproj(const u16* __restrict__ ab,
                                                  const u16* __restrict__ wo,
                                                  const float* __restrict__ bo,
                                                  float* __restrict__ out) {
  __shared__ u16 lA[4096], lB[4096];
  const int m0 = blockIdx.y * 128, n0 = blockIdx.x * 128;
  f32x4 acc[4][4];
#pragma unroll
  for (int i = 0; i < 4; ++i)
#pragma unroll
    for (int j = 0; j < 4; ++j) acc[i][j] = (f32x4){0.f, 0.f, 0.f, 0.f};
  gemm_tile(ab, wo, lA, lB, m0, n0, acc);

  const int t = threadIdx.x;
  const int wave = t >> 6, lane = t & 63, lr = lane & 15, lg = lane >> 4;
  const int wr = wave >> 1, wc = wave & 1;
  float bb[4];
#pragma unroll
  for (int cb = 0; cb < 4; ++cb) bb[cb] = bo[n0 + wc * 64 + cb * 16 + lr];
#pragma unroll
  for (int rb = 0; rb < 4; ++rb)
#pragma unroll
    for (int cb = 0; cb < 4; ++cb)
#pragma unroll
      for (int r = 0; r < 4; ++r) {
        int m = m0 + wr * 64 + rb * 16 + lg * 4 + r;
        int n = n0 + wc * 64 + cb * 16 + lr;
        out[m * 1024 + n] = acc[rb][cb][r] + bb[cb];
      }
}

// ---------------------------------------------------------------------------
// Attention: one block per (b,h). 512 thr / 8 waves. K[512][64] and
// V^T[64][512] resident in LDS (XOR slot-swizzle: elem = row*RS + (slot^(row&7))*8).
// Each wave: 4 q-tiles of 16 rows; S (16x512) in regs; softmax in-register;
// P re-fragmented via 2KB/wave LDS buffer for PV MFMA. O = P V / rowsum.
// ---------------------------------------------------------------------------
__global__ __launch_bounds__(512, 2) void attn_kernel(
    const u16* __restrict__ qb, const u16* __restrict__ kb,
    const u16* __restrict__ vb, u16* __restrict__ ab) {
  __shared__ u16 lK[32768];   // [512 rows][64] swizzled (64 KB)
  __shared__ u16 lV[32768];   // [64 rows][512] swizzled (64 KB)
  __shared__ u16 lP[8192];    // 8 waves x [16][64] swizzled (16 KB)
  const int t = threadIdx.x;
  const int bh = blockIdx.x;
  const int b_ = bh >> 4, h_ = bh & 15;
  const u16* kg = kb + bh * 32768;
  const u16* vg = vb + bh * 32768;
#pragma unroll
  for (int i = 0; i < 8; ++i) {
    int row = i * 64 + (t >> 3), slot = t & 7;            // K: 64 rows/iter
    short8 kv = *(const short8*)(kg + row * 64 + slot * 8);
    *(short8*)(lK + row * 64 + ((slot ^ (row & 7)) << 3)) = kv;
    int vrow = i * 8 + (t >> 6), vslot = t & 63;          // V^T: 8 rows/iter
    short8 vv = *(const short8*)(vg + vrow * 512 + vslot * 8);
    *(short8*)(lV + vrow * 512 + ((vslot ^ (vrow & 7)) << 3)) = vv;
  }
  __syncthreads();

  const int wv_ = t >> 6, lane = t & 63, lr = lane & 15, lg = lane >> 4;
  u16* lPw = lP + wv_ * 1024;
  const u16* qg = qb + bh * 32768;
  const float sc = 0.125f * 1.44269504088896f;  // (1/sqrt(64)) * log2(e)

#pragma unroll 1
  for (int qi = 0; qi < 4; ++qi) {
    const int qrow = (wv_ * 4 + qi) * 16;
    // Q A-frags straight from global: row=lr, k=lg*8..
    short8 a0 = *(const short8*)(qg + (qrow + lr) * 64 + lg * 8);
    short8 a1 = *(const short8*)(qg + (qrow + lr) * 64 + 32 + lg * 8);
    f32x4 s[32];
#pragma unroll
    for (int f = 0; f < 32; ++f) {
      const u16* kr = lK + (f * 16 + lr) * 64;
      short8 k0 = *(const short8*)(kr + ((lg ^ (lr & 7)) << 3));
      short8 k1 = *(const short8*)(kr + (((4 + lg) ^ (lr & 7)) << 3));
      f32x4 z4 = (f32x4){0.f, 0.f, 0.f, 0.f};
      z4 = __builtin_amdgcn_mfma_f32_16x16x32_bf16(a0, k0, z4, 0, 0, 0);
      z4 = __builtin_amdgcn_mfma_f32_16x16x32_bf16(a1, k1, z4, 0, 0, 0);
      s[f] = z4;                      // D: row q = lg*4+reg, col k = f*16+lr
    }
    // softmax over 512 cols; rows are (lane-local reg r) x (16-lane groups)
    float inv[4];
#pragma unroll
    for (int r = 0; r < 4; ++r) {
      float m_ = s[0][r];
#pragma unroll
      for (int f = 1; f < 32; ++f) m_ = fmaxf(m_, s[f][r]);
      m_ = fmaxf(m_, __shfl_xor(m_, 1));
      m_ = fmaxf(m_, __shfl_xor(m_, 2));
      m_ = fmaxf(m_, __shfl_xor(m_, 4));
      m_ = fmaxf(m_, __shfl_xor(m_, 8));
      float sm = 0.f;
#pragma unroll
      for (int f = 0; f < 32; ++f) {
        float e = exp2f((s[f][r] - m_) * sc);
        s[f][r] = e;
        sm += e;
      }
      sm += __shfl_xor(sm, 1);
      sm += __shfl_xor(sm, 2);
      sm += __shfl_xor(sm, 4);
      sm += __shfl_xor(sm, 8);
      inv[r] = 1.f / sm;
    }
    // PV: 8 chunks of 64 k-cols; P chunk -> LDS -> A-frags; V^T rows as B-frags
    f32x4 o[4];
#pragma unroll
    for (int i = 0; i < 4; ++i) o[i] = (f32x4){0.f, 0.f, 0.f, 0.f};
#pragma unroll
    for (int ch = 0; ch < 8; ++ch) {
#pragma unroll
      for (int cf = 0; cf < 4; ++cf)
#pragma unroll
        for (int r = 0; r < 4; ++r) {
          int q = lg * 4 + r, kc = cf * 16 + lr;
          lPw[q * 64 + (((kc >> 3) ^ (q & 7)) << 3) + (kc & 7)] =
              f2bf(s[ch * 4 + cf][r]);
        }
      asm volatile("s_waitcnt lgkmcnt(0)" ::: "memory");
      const u16* pr = lPw + lr * 64;
      short8 pa0 = *(const short8*)(pr + ((lg ^ (lr & 7)) << 3));
      short8 pa1 = *(const short8*)(pr + (((4 + lg) ^ (lr & 7)) << 3));
#pragma unroll
      for (int df = 0; df < 4; ++df) {
        const u16* vr = lV + (df * 16 + lr) * 512;
        short8 v0 = *(const short8*)(vr + (((ch * 8 + lg) ^ (lr & 7)) << 3));
        short8 v1 =
            *(const short8*)(vr + (((ch * 8 + 4 + lg) ^ (lr & 7)) << 3));
        o[df] = __builtin_amdgcn_mfma_f32_16x16x32_bf16(pa0, v0, o[df], 0, 0, 0);
        o[df] = __builtin_amdgcn_mfma_f32_16x16x32_bf16(pa1, v1, o[df], 0, 0, 0);
      }
    }
    // store O/rowsum to attn-out [b, c, h*64+d] bf16
#pragma unroll
    for (int df = 0; df < 4; ++df)
#pragma unroll
      for (int r = 0; r < 4; ++r) {
        int q = qrow + lg * 4 + r, dd = df * 16 + lr;
        ab[(b_ * 512 + q) * 1024 + h_ * 64 + dd] = f2bf(o[df][r] * inv[r]);
      }
  }
}

// ---------------------------------------------------------------------------
extern "C" void kernel_launch(void* const* d_in, const int* in_sizes, int n_in,
                              void* d_out, int out_size, void* d_ws,
                              size_t ws_size, hipStream_t stream) {
  (void)in_sizes; (void)n_in; (void)out_size;
  const float* x  = (const float*)d_in[0];
  const float* Wq = (const float*)d_in[1];
  const float* bq = (const float*)d_in[2];
  const float* Wk = (const float*)d_in[3];
  const float* bk = (const float*)d_in[4];
  const float* Wv = (const float*)d_in[5];
  const float* bv = (const float*)d_in[6];
  const float* Wo = (const float*)d_in[7];
  const float* bo = (const float*)d_in[8];
  float* out = (float*)d_out;

  // Workspace (bf16 elems): xb (reused as attn-out) | Wq,Wk,Wv,Wo | Q | K | V^T
  if (ws_size < 75497472u) return;  // 72 MB needed
  u16* xb  = (u16*)d_ws;            // 8388608 elems, dead after QKV GEMM
  u16* wqb = xb + 8388608;
  u16* wkb = wqb + 1048576;
  u16* wvb = wkb + 1048576;
  u16* wob = wvb + 1048576;
  u16* qbuf = wob + 1048576;        // [b,h,c,d]
  u16* kbuf = qbuf + 8388608;       // [b,h,c,d]
  u16* vbuf = kbuf + 8388608;       // [b,h,d,c]
  u16* abuf = xb;                   // attn-out [b,c,e], aliases dead xb

  cvt_bf16<<<8192, 256, 0, stream>>>(x, xb, 2097152);
  cvt_bf16<<<1024, 256, 0, stream>>>(Wq, wqb, 262144);
  cvt_bf16<<<1024, 256, 0, stream>>>(Wk, wkb, 262144);
  cvt_bf16<<<1024, 256, 0, stream>>>(Wv, wvb, 262144);
  cvt_bf16<<<1024, 256, 0, stream>>>(Wo, wob, 262144);

  gemm_qkv<<<dim3(8, 64, 3), 256, 0, stream>>>(xb, wqb, wkb, wvb, bq, bk, bv,
                                               qbuf, kbuf, vbuf);
  attn_kernel<<<256, 512, 0, stream>>>(qbuf, kbuf, vbuf, abuf);
  gemm_oproj<<<dim3(8, 64, 1), 256, 0, stream>>>(abuf, wob, bo, out);
}

// Round 2
// 174.318 us; speedup vs baseline: 1.0455x; 1.0455x over previous
//
#include <hip/hip_runtime.h>

// ---------------------------------------------------------------------------
// SpatialWiseSelfAttention on MI355X (gfx950), bf16 MFMA pipeline.
//   x[16,512,32,32] -> xf[8192,1024]
//   Q/K/V = xf @ W*.T + b*      (NT GEMM, bf16 inputs, fp32 accum)
//   per (b,h): S = Q K^T / 8 ; P = softmax(S) ; O = P V
//   out = O @ Wo.T + bo  (fp32 out)
// GEMMs use the 4-phase/K-tile pipelined template (T2 swizzle + counted vmcnt
// + setprio), 3-buffer LDS rotation, prefetch distance 2.
// ---------------------------------------------------------------------------

typedef unsigned short u16;
typedef __attribute__((ext_vector_type(8))) short short8;   // 8 bf16 = 4 VGPR
typedef __attribute__((ext_vector_type(4))) float f32x4;
typedef __attribute__((ext_vector_type(4))) unsigned short u16x4;

#define MFMA16(a, b, c) __builtin_amdgcn_mfma_f32_16x16x32_bf16(a, b, c, 0, 0, 0)

__device__ __forceinline__ u16 f2bf(float x) {            // RNE f32->bf16
  unsigned u = __float_as_uint(x);
  u += 0x7FFFu + ((u >> 16) & 1u);
  return (u16)(u >> 16);
}

__device__ __forceinline__ void async16(const void* g, void* l) {
  // 16B global->LDS direct; LDS dest = wave-uniform base + lane*16.
  __builtin_amdgcn_global_load_lds(
      (__attribute__((address_space(1))) unsigned int*)(g),
      (__attribute__((address_space(3))) unsigned int*)(l), 16, 0, 0);
}

// ---------------------------------------------------------------------------
// fp32 -> bf16 conversion, 4 elems/thread
// ---------------------------------------------------------------------------
__global__ __launch_bounds__(256) void cvt_bf16(const float* __restrict__ s,
                                                u16* __restrict__ d, int n4) {
  int i = blockIdx.x * 256 + threadIdx.x;
  if (i >= n4) return;
  f32x4 v = ((const f32x4*)s)[i];
  u16x4 o;
#pragma unroll
  for (int j = 0; j < 4; ++j) o[j] = f2bf(v[j]);
  ((u16x4*)d)[i] = o;
}

// ---------------------------------------------------------------------------
// Pipelined NT GEMM core. C-tile 128(M)x256(N), BK=64, K=1024 (16 K-tiles).
// 512 thr / 8 waves as 2(M)x4(N); per-wave 64x64 = 4x4 frags of 16x16x32.
// LDS: 3 buffers x { A[128][64] + B[256][64] } bf16, XOR-swizzled
//   (slot ^= row&7 at 16B granularity), staged linearly by global_load_lds
//   from a pre-swizzled global source. 144 KiB total.
// Per K-tile: 4 phases x {ds_read frags | stage issue | barrier | 8 MFMA |
//   barrier}; boundary s_waitcnt vmcnt(6) (counted, never 0 until drain).
// ---------------------------------------------------------------------------
__device__ __forceinline__ void gemm8(const u16* __restrict__ A,
                                      const u16* __restrict__ W,
                                      int m0, int n0, u16* lds,
                                      f32x4 acc[4][4]) {
  const int t = threadIdx.x;
  const int wave = t >> 6, lane = t & 63, lr = lane & 15, lg = lane >> 4;
  const int wr = wave >> 2, wn = wave & 3;
  // staging: thread t covers LDS row srow = t>>3, 16B slot s = t&7 of each
  // 64-row panel; pre-swizzled source col-chunk c = s ^ (srow&7).
  const int srow = t >> 3;
  const int scol = ((t & 7) ^ ((t >> 3) & 7)) << 3;
  const u16* gA = A + (size_t)(m0 + srow) * 1024 + scol;
  const u16* gB = W + (size_t)(n0 + srow) * 1024 + scol;
  u16* stA = lds + wave * 512;          // + buf*24576 (+4096 for rows 64..127)
  u16* stB = lds + 8192 + wave * 512;   // + buf*24576 + j*4096
  // fragment read bases (elem offsets within buffer):
  const int aoff = (wr * 64 + lr) * 64;   // + m*1024
  const int boff = (wn * 64 + lr) * 64;   // + n*1024
  const int sw0 = (lg ^ (lr & 7)) << 3;         // k-half 0
  const int sw1 = ((4 ^ lg) ^ (lr & 7)) << 3;   // k-half 1

#define STAGEA(buf, k0)                                   \
  {                                                       \
    async16(gA + (k0), stA + (buf) * 24576);              \
    async16(gA + 65536 + (k0), stA + (buf) * 24576 + 4096); \
  }
#define STAGEB2(buf, k0, j)                                             \
  {                                                                     \
    async16(gB + (j) * 65536 + (k0), stB + (buf) * 24576 + (j) * 4096); \
    async16(gB + ((j) + 1) * 65536 + (k0),                              \
            stB + (buf) * 24576 + ((j) + 1) * 4096);                    \
  }

  // Prologue: stage K-tiles 0 and 1 (6 loads each).
  STAGEA(0, 0); STAGEB2(0, 0, 0); STAGEB2(0, 0, 2);
  STAGEA(1, 64); STAGEB2(1, 64, 0); STAGEB2(1, 64, 2);
  asm volatile("s_waitcnt vmcnt(6)" ::: "memory");  // tile 0 complete
  __builtin_amdgcn_s_barrier();

#pragma unroll
  for (int tt = 0; tt < 16; ++tt) {
    const int cb = tt % 3, nb = (tt + 2) % 3;
    const bool st = (tt < 14);
    const int kn = (tt + 2) * 64;
    const u16* la = lds + cb * 24576 + aoff;
    const u16* lb = lds + cb * 24576 + 8192 + boff;
    short8 av[4], b0, b1;
    // ---- phase 0: k-half 0, n-frags 0,1 ----
#pragma unroll
    for (int m = 0; m < 4; ++m) av[m] = *(const short8*)(la + m * 1024 + sw0);
    b0 = *(const short8*)(lb + 0 * 1024 + sw0);
    b1 = *(const short8*)(lb + 1 * 1024 + sw0);
    if (st) STAGEA(nb, kn);
    __builtin_amdgcn_s_barrier();
    __builtin_amdgcn_s_setprio(1);
#pragma unroll
    for (int m = 0; m < 4; ++m) {
      acc[m][0] = MFMA16(av[m], b0, acc[m][0]);
      acc[m][1] = MFMA16(av[m], b1, acc[m][1]);
    }
    __builtin_amdgcn_s_setprio(0);
    __builtin_amdgcn_s_barrier();
    // ---- phase 1: k-half 0, n-frags 2,3 ----
    b0 = *(const short8*)(lb + 2 * 1024 + sw0);
    b1 = *(const short8*)(lb + 3 * 1024 + sw0);
    if (st) STAGEB2(nb, kn, 0);
    __builtin_amdgcn_s_barrier();
    __builtin_amdgcn_s_setprio(1);
#pragma unroll
    for (int m = 0; m < 4; ++m) {
      acc[m][2] = MFMA16(av[m], b0, acc[m][2]);
      acc[m][3] = MFMA16(av[m], b1, acc[m][3]);
    }
    __builtin_amdgcn_s_setprio(0);
    __builtin_amdgcn_s_barrier();
    // ---- phase 2: k-half 1, n-frags 0,1 ----
#pragma unroll
    for (int m = 0; m < 4; ++m) av[m] = *(const short8*)(la + m * 1024 + sw1);
    b0 = *(const short8*)(lb + 0 * 1024 + sw1);
    b1 = *(const short8*)(lb + 1 * 1024 + sw1);
    if (st) STAGEB2(nb, kn, 2);
    __builtin_amdgcn_s_barrier();
    __builtin_amdgcn_s_setprio(1);
#pragma unroll
    for (int m = 0; m < 4; ++m) {
      acc[m][0] = MFMA16(av[m], b0, acc[m][0]);
      acc[m][1] = MFMA16(av[m], b1, acc[m][1]);
    }
    __builtin_amdgcn_s_setprio(0);
    __builtin_amdgcn_s_barrier();
    // ---- phase 3: k-half 1, n-frags 2,3 ----
    b0 = *(const short8*)(lb + 2 * 1024 + sw1);
    b1 = *(const short8*)(lb + 3 * 1024 + sw1);
    __builtin_amdgcn_s_barrier();
    __builtin_amdgcn_s_setprio(1);
#pragma unroll
    for (int m = 0; m < 4; ++m) {
      acc[m][2] = MFMA16(av[m], b0, acc[m][2]);
      acc[m][3] = MFMA16(av[m], b1, acc[m][3]);
    }
    __builtin_amdgcn_s_setprio(0);
    // boundary: ensure next tile's 6 loads done; keep tile-after-next's 6
    // (issued above) in flight. Last tile: full drain is free (nothing newer).
    if (tt < 14) {
      asm volatile("s_waitcnt vmcnt(6)" ::: "memory");
    } else {
      asm volatile("s_waitcnt vmcnt(0)" ::: "memory");
    }
    __builtin_amdgcn_s_barrier();
  }
#undef STAGEA
#undef STAGEB2
}

// QKV fused: linear grid 768 = 64 m-tiles x 4 n-tiles x 3 z, XCD-swizzled.
// Q,K out layout [b,h,c,d]; V out [b,h,d,c] (transposed for attention PV).
__global__ __launch_bounds__(512, 1) void gemm_qkv(
    const u16* __restrict__ xb, const u16* __restrict__ wq,
    const u16* __restrict__ wk, const u16* __restrict__ wv,
    const float* __restrict__ bq, const float* __restrict__ bk,
    const float* __restrict__ bv, u16* __restrict__ qo, u16* __restrict__ ko,
    u16* __restrict__ vo) {
  __shared__ u16 lds[73728];  // 144 KiB
  const int id = blockIdx.x;
  const int lid = (id & 7) * 96 + (id >> 3);  // bijective XCD swizzle (768%8==0)
  const int z = lid >> 8;
  const int rem = lid & 255;
  const int m0 = (rem >> 2) * 128, n0 = (rem & 3) * 256;
  const u16* W = (z == 0) ? wq : (z == 1) ? wk : wv;
  const float* bias = (z == 0) ? bq : (z == 1) ? bk : bv;
  u16* outp = (z == 0) ? qo : (z == 1) ? ko : vo;
  f32x4 acc[4][4];
#pragma unroll
  for (int i = 0; i < 4; ++i)
#pragma unroll
    for (int j = 0; j < 4; ++j) acc[i][j] = (f32x4){0.f, 0.f, 0.f, 0.f};
  gemm8(xb, W, m0, n0, lds, acc);

  const int t = threadIdx.x;
  const int wave = t >> 6, lane = t & 63, lr = lane & 15, lg = lane >> 4;
  const int wr = wave >> 2, wn = wave & 3;
  float bb[4];
#pragma unroll
  for (int nf = 0; nf < 4; ++nf) bb[nf] = bias[n0 + wn * 64 + nf * 16 + lr];
#pragma unroll
  for (int mf = 0; mf < 4; ++mf)
#pragma unroll
    for (int nf = 0; nf < 4; ++nf)
#pragma unroll
      for (int r = 0; r < 4; ++r) {
        int m = m0 + wr * 64 + mf * 16 + lg * 4 + r;  // D: row=(lane>>4)*4+reg
        int n = n0 + wn * 64 + nf * 16 + lr;          //    col=lane&15
        float val = acc[mf][nf][r] + bb[nf];
        int b_ = m >> 9, c = m & 511, h = n >> 6, dd = n & 63;
        int idx = (z == 2) ? ((((b_ << 4) + h) << 15) + (dd << 9) + c)
                           : ((((b_ << 4) + h) << 15) + (c << 6) + dd);
        outp[idx] = f2bf(val);
      }
}

// Output projection: fp32 out + bias, linear [8192][1024]. Grid 256.
__global__ __launch_bounds__(512, 1) void gemm_oproj(const u16* __restrict__ ab,
                                                     const u16* __restrict__ wo,
                                                     const float* __restrict__ bo,
                                                     float* __restrict__ out) {
  __shared__ u16 lds[73728];
  const int id = blockIdx.x;
  const int lid = (id & 7) * 32 + (id >> 3);  // 256%8==0
  const int m0 = (lid >> 2) * 128, n0 = (lid & 3) * 256;
  f32x4 acc[4][4];
#pragma unroll
  for (int i = 0; i < 4; ++i)
#pragma unroll
    for (int j = 0; j < 4; ++j) acc[i][j] = (f32x4){0.f, 0.f, 0.f, 0.f};
  gemm8(ab, wo, m0, n0, lds, acc);

  const int t = threadIdx.x;
  const int wave = t >> 6, lane = t & 63, lr = lane & 15, lg = lane >> 4;
  const int wr = wave >> 2, wn = wave & 3;
  float bb[4];
#pragma unroll
  for (int nf = 0; nf < 4; ++nf) bb[nf] = bo[n0 + wn * 64 + nf * 16 + lr];
#pragma unroll
  for (int mf = 0; mf < 4; ++mf)
#pragma unroll
    for (int nf = 0; nf < 4; ++nf)
#pragma unroll
      for (int r = 0; r < 4; ++r) {
        int m = m0 + wr * 64 + mf * 16 + lg * 4 + r;
        int n = n0 + wn * 64 + nf * 16 + lr;
        out[m * 1024 + n] = acc[mf][nf][r] + bb[nf];
      }
}

// ---------------------------------------------------------------------------
// Attention: one block per (b,h). 512 thr / 8 waves. K[512][64] and
// V^T[64][512] resident in LDS (XOR slot-swizzle: elem = row*RS + (slot^(row&7))*8).
// Each wave: 4 q-tiles of 16 rows; S (16x512) in regs; softmax in-register;
// P re-fragmented via 2KB/wave LDS buffer for PV MFMA. O = P V / rowsum.
// ---------------------------------------------------------------------------
__global__ __launch_bounds__(512, 2) void attn_kernel(
    const u16* __restrict__ qb, const u16* __restrict__ kb,
    const u16* __restrict__ vb, u16* __restrict__ ab) {
  __shared__ u16 lK[32768];   // [512 rows][64] swizzled (64 KB)
  __shared__ u16 lV[32768];   // [64 rows][512] swizzled (64 KB)
  __shared__ u16 lP[8192];    // 8 waves x [16][64] swizzled (16 KB)
  const int t = threadIdx.x;
  const int bh = blockIdx.x;
  const int b_ = bh >> 4, h_ = bh & 15;
  const u16* kg = kb + bh * 32768;
  const u16* vg = vb + bh * 32768;
#pragma unroll
  for (int i = 0; i < 8; ++i) {
    int row = i * 64 + (t >> 3), slot = t & 7;            // K: 64 rows/iter
    short8 kv = *(const short8*)(kg + row * 64 + slot * 8);
    *(short8*)(lK + row * 64 + ((slot ^ (row & 7)) << 3)) = kv;
    int vrow = i * 8 + (t >> 6), vslot = t & 63;          // V^T: 8 rows/iter
    short8 vv = *(const short8*)(vg + vrow * 512 + vslot * 8);
    *(short8*)(lV + vrow * 512 + ((vslot ^ (vrow & 7)) << 3)) = vv;
  }
  __syncthreads();

  const int wv_ = t >> 6, lane = t & 63, lr = lane & 15, lg = lane >> 4;
  u16* lPw = lP + wv_ * 1024;
  const u16* qg = qb + bh * 32768;
  const float sc = 0.125f * 1.44269504088896f;  // (1/sqrt(64)) * log2(e)

#pragma unroll 1
  for (int qi = 0; qi < 4; ++qi) {
    const int qrow = (wv_ * 4 + qi) * 16;
    // Q A-frags straight from global: row=lr, k=lg*8..
    short8 a0 = *(const short8*)(qg + (qrow + lr) * 64 + lg * 8);
    short8 a1 = *(const short8*)(qg + (qrow + lr) * 64 + 32 + lg * 8);
    f32x4 s[32];
#pragma unroll
    for (int f = 0; f < 32; ++f) {
      const u16* kr = lK + (f * 16 + lr) * 64;
      short8 k0 = *(const short8*)(kr + ((lg ^ (lr & 7)) << 3));
      short8 k1 = *(const short8*)(kr + (((4 + lg) ^ (lr & 7)) << 3));
      f32x4 z4 = (f32x4){0.f, 0.f, 0.f, 0.f};
      z4 = MFMA16(a0, k0, z4);
      z4 = MFMA16(a1, k1, z4);
      s[f] = z4;                      // D: row q = lg*4+reg, col k = f*16+lr
    }
    // softmax over 512 cols; rows are (lane-local reg r) x (16-lane groups)
    float inv[4];
#pragma unroll
    for (int r = 0; r < 4; ++r) {
      float m_ = s[0][r];
#pragma unroll
      for (int f = 1; f < 32; ++f) m_ = fmaxf(m_, s[f][r]);
      m_ = fmaxf(m_, __shfl_xor(m_, 1));
      m_ = fmaxf(m_, __shfl_xor(m_, 2));
      m_ = fmaxf(m_, __shfl_xor(m_, 4));
      m_ = fmaxf(m_, __shfl_xor(m_, 8));
      float sm = 0.f;
#pragma unroll
      for (int f = 0; f < 32; ++f) {
        float e = exp2f((s[f][r] - m_) * sc);
        s[f][r] = e;
        sm += e;
      }
      sm += __shfl_xor(sm, 1);
      sm += __shfl_xor(sm, 2);
      sm += __shfl_xor(sm, 4);
      sm += __shfl_xor(sm, 8);
      inv[r] = 1.f / sm;
    }
    // PV: 8 chunks of 64 k-cols; P chunk -> LDS -> A-frags; V^T rows as B-frags
    f32x4 o[4];
#pragma unroll
    for (int i = 0; i < 4; ++i) o[i] = (f32x4){0.f, 0.f, 0.f, 0.f};
#pragma unroll
    for (int ch = 0; ch < 8; ++ch) {
#pragma unroll
      for (int cf = 0; cf < 4; ++cf)
#pragma unroll
        for (int r = 0; r < 4; ++r) {
          int q = lg * 4 + r, kc = cf * 16 + lr;
          lPw[q * 64 + (((kc >> 3) ^ (q & 7)) << 3) + (kc & 7)] =
              f2bf(s[ch * 4 + cf][r]);
        }
      asm volatile("s_waitcnt lgkmcnt(0)" ::: "memory");
      const u16* pr = lPw + lr * 64;
      short8 pa0 = *(const short8*)(pr + ((lg ^ (lr & 7)) << 3));
      short8 pa1 = *(const short8*)(pr + (((4 + lg) ^ (lr & 7)) << 3));
#pragma unroll
      for (int df = 0; df < 4; ++df) {
        const u16* vr = lV + (df * 16 + lr) * 512;
        short8 v0 = *(const short8*)(vr + (((ch * 8 + lg) ^ (lr & 7)) << 3));
        short8 v1 =
            *(const short8*)(vr + (((ch * 8 + 4 + lg) ^ (lr & 7)) << 3));
        o[df] = MFMA16(pa0, v0, o[df]);
        o[df] = MFMA16(pa1, v1, o[df]);
      }
    }
    // store O/rowsum to attn-out [b, c, h*64+d] bf16
#pragma unroll
    for (int df = 0; df < 4; ++df)
#pragma unroll
      for (int r = 0; r < 4; ++r) {
        int q = qrow + lg * 4 + r, dd = df * 16 + lr;
        ab[(b_ * 512 + q) * 1024 + h_ * 64 + dd] = f2bf(o[df][r] * inv[r]);
      }
  }
}

// ---------------------------------------------------------------------------
extern "C" void kernel_launch(void* const* d_in, const int* in_sizes, int n_in,
                              void* d_out, int out_size, void* d_ws,
                              size_t ws_size, hipStream_t stream) {
  (void)in_sizes; (void)n_in; (void)out_size;
  const float* x  = (const float*)d_in[0];
  const float* Wq = (const float*)d_in[1];
  const float* bq = (const float*)d_in[2];
  const float* Wk = (const float*)d_in[3];
  const float* bk = (const float*)d_in[4];
  const float* Wv = (const float*)d_in[5];
  const float* bv = (const float*)d_in[6];
  const float* Wo = (const float*)d_in[7];
  const float* bo = (const float*)d_in[8];
  float* out = (float*)d_out;

  // Workspace (bf16 elems): xb (reused as attn-out) | Wq,Wk,Wv,Wo | Q | K | V^T
  if (ws_size < 75497472u) return;  // 72 MB needed
  u16* xb  = (u16*)d_ws;            // 8388608 elems, dead after QKV GEMM
  u16* wqb = xb + 8388608;
  u16* wkb = wqb + 1048576;
  u16* wvb = wkb + 1048576;
  u16* wob = wvb + 1048576;
  u16* qbuf = wob + 1048576;        // [b,h,c,d]
  u16* kbuf = qbuf + 8388608;       // [b,h,c,d]
  u16* vbuf = kbuf + 8388608;       // [b,h,d,c]
  u16* abuf = xb;                   // attn-out [b,c,e], aliases dead xb

  cvt_bf16<<<8192, 256, 0, stream>>>(x, xb, 2097152);
  cvt_bf16<<<1024, 256, 0, stream>>>(Wq, wqb, 262144);
  cvt_bf16<<<1024, 256, 0, stream>>>(Wk, wkb, 262144);
  cvt_bf16<<<1024, 256, 0, stream>>>(Wv, wvb, 262144);
  cvt_bf16<<<1024, 256, 0, stream>>>(Wo, wob, 262144);

  gemm_qkv<<<768, 512, 0, stream>>>(xb, wqb, wkb, wvb, bq, bk, bv,
                                    qbuf, kbuf, vbuf);
  attn_kernel<<<256, 512, 0, stream>>>(qbuf, kbuf, vbuf, abuf);
  gemm_oproj<<<256, 512, 0, stream>>>(abuf, wob, bo, out);
}